// Round 9
// baseline (811.576 us; speedup 1.0000x reference)
//
#include <hip/hip_runtime.h>

#define NADDR 400000
#define NTX   400000
#define NEDGE 1500000
#define FIN   64
#define HID   32
#define NB    1563        // buckets per node type; 256 nodes per bucket
#define LSTR  36          // LDS row stride (floats): 144 B, 16B-aligned rows
#define NND   400000      // nodes per type
#define NHALF 200000      // NND / 2 (R=2 rows per thread)

static inline int cdiv_host(long a, int b) { return (int)((a + b - 1) / b); }

// ================= bucketed CSR build (verified round-4 chain) ==============

__global__ void k_hist(const int* __restrict__ at_dst, const int* __restrict__ ta_dst,
                       int* __restrict__ bcnt /*[2*NB]*/, int GH) {
    __shared__ int h[NB];
    bool wh = blockIdx.x >= GH;
    int blk = blockIdx.x - (wh ? GH : 0);
    const int* dst = wh ? ta_dst : at_dst;
    for (int i = threadIdx.x; i < NB; i += 256) h[i] = 0;
    __syncthreads();
    for (long e = (long)blk * 256 + threadIdx.x; e < NEDGE; e += (long)GH * 256)
        atomicAdd(&h[dst[e] >> 8], 1);
    __syncthreads();
    int* g = bcnt + (wh ? NB : 0);
    for (int i = threadIdx.x; i < NB; i += 256) {
        int v = h[i];
        if (v) atomicAdd(&g[i], v);
    }
}

__global__ void k_scan_nb(const int* __restrict__ bcnt, int* __restrict__ bbase,
                          int* __restrict__ gcur) {
    __shared__ int sm[256];
    __shared__ int carry;
    int w = blockIdx.x;
    int t = threadIdx.x;
    if (t == 0) carry = 0;
    __syncthreads();
    for (int base = 0; base < NB; base += 256) {
        int i = base + t;
        int v = (i < NB) ? bcnt[w * NB + i] : 0;
        sm[t] = v;
        __syncthreads();
        for (int off = 1; off < 256; off <<= 1) {
            int x = (t >= off) ? sm[t - off] : 0;
            __syncthreads();
            sm[t] += x;
            __syncthreads();
        }
        int excl = sm[t] - v + carry;
        if (i < NB) { bbase[w * (NB + 1) + i] = excl; gcur[w * NB + i] = excl; }
        int tot = sm[255];
        __syncthreads();
        if (t == 0) carry += tot;
        __syncthreads();
    }
    if (t == 0) bbase[w * (NB + 1) + NB] = NEDGE;
}

__global__ void k_dist(const int* __restrict__ ei_at, const int* __restrict__ ei_ta,
                       int* __restrict__ gcur, unsigned* __restrict__ eb_at,
                       unsigned* __restrict__ eb_ta, int GD) {
    __shared__ int h[NB];
    __shared__ int bs[NB];
    bool wh = blockIdx.x >= GD;
    int blk = blockIdx.x - (wh ? GD : 0);
    const int* ei = wh ? ei_ta : ei_at;
    unsigned* eb = wh ? eb_ta : eb_at;
    for (int i = threadIdx.x; i < NB; i += 256) h[i] = 0;
    __syncthreads();
    long e0 = (long)blk * 256 + threadIdx.x;
    long stride = (long)GD * 256;
    for (long e = e0; e < NEDGE; e += stride)
        atomicAdd(&h[ei[NEDGE + e] >> 8], 1);
    __syncthreads();
    int* gc = gcur + (wh ? NB : 0);
    for (int i = threadIdx.x; i < NB; i += 256) {
        int c = h[i];
        bs[i] = c ? atomicAdd(&gc[i], c) : 0;
        h[i] = 0;
    }
    __syncthreads();
    for (long e = e0; e < NEDGE; e += stride) {
        int d = ei[NEDGE + e];
        int s = ei[e];
        int b = d >> 8;
        int r = atomicAdd(&h[b], 1);
        eb[bs[b] + r] = ((unsigned)s << 8) | (unsigned)(d & 255);
    }
}

__global__ void k_csrb(const unsigned* __restrict__ eb_at, const unsigned* __restrict__ eb_ta,
                       const int* __restrict__ bbase,
                       int* __restrict__ rp_tx, int* __restrict__ rp_ad,
                       int* __restrict__ col_at, int* __restrict__ col_ta) {
    __shared__ int deg[256];
    __shared__ int cur[256];
    __shared__ int sm[256];
    bool wh = blockIdx.x >= NB;
    int b = blockIdx.x - (wh ? NB : 0);
    const unsigned* eb = wh ? eb_ta : eb_at;
    int* rp  = wh ? rp_ad  : rp_tx;
    int* col = wh ? col_ta : col_at;
    const int* bb = bbase + (wh ? (NB + 1) : 0);
    int e0 = bb[b], e1 = bb[b + 1];
    int t = threadIdx.x;
    deg[t] = 0;
    __syncthreads();
    for (int e = e0 + t; e < e1; e += 256)
        atomicAdd(&deg[eb[e] & 255], 1);
    __syncthreads();
    int v = deg[t];
    sm[t] = v;
    __syncthreads();
    for (int off = 1; off < 256; off <<= 1) {
        int x = (t >= off) ? sm[t - off] : 0;
        __syncthreads();
        sm[t] += x;
        __syncthreads();
    }
    int excl = sm[t] - v;
    int node = b * 256 + t;
    if (node < NND) rp[node] = e0 + excl;
    cur[t] = e0 + excl;
    __syncthreads();
    for (int e = e0 + t; e < e1; e += 256) {
        unsigned p = eb[e];
        int idx = atomicAdd(&cur[p & 255], 1);
        col[idx] = (int)(p >> 8);
    }
    if (t == 0 && b == 0) rp[NND] = NEDGE;
}

// ================= L1 dense pre-transform (row-major input, single out) =====
// 128 threads stage 256 rows x 32-feat tiles into LDS (fully coalesced, each
// 128B line fetched once). Thread t computes rows t and t+128 with register-
// resident row caches and accumulators (R=2: each weight value reused twice,
// two independent FMA chains). launch_bounds(,2) leaves VGPR headroom.
template<int F>
__global__ __launch_bounds__(128, 2)
void k_preS(const float* __restrict__ x, const float* __restrict__ w,
            const float* __restrict__ b, float* __restrict__ out, int n) {
    __shared__ alignas(16) float xs[256 * LSTR];
    int t = threadIdx.x;
    long row0 = (long)blockIdx.x * 256;

    float a0[HID], a1[HID];
#pragma unroll
    for (int j = 0; j < HID; ++j) { float bv = b ? b[j] : 0.0f; a0[j] = bv; a1[j] = bv; }

    for (int kt = 0; kt < F / 32; ++kt) {
        if (kt) __syncthreads();
        // ---- stage 256 rows x 32 floats, coalesced ----
#pragma unroll
        for (int sub = 0; sub < 16; ++sub) {
            int f = sub * 128 + t;
            int r = f >> 3, k4 = f & 7;
            long gr = row0 + r;
            if (gr >= n) gr = n - 1;
            *(float4*)(&xs[r * LSTR + k4 * 4]) = *(const float4*)(x + gr * F + kt * 32 + k4 * 4);
        }
        __syncthreads();
        // ---- preload both rows into registers ----
        float xA[32], xB[32];
#pragma unroll
        for (int q = 0; q < 8; ++q) {
            float4 v = *(const float4*)(&xs[t * LSTR + q * 4]);
            xA[q * 4] = v.x; xA[q * 4 + 1] = v.y; xA[q * 4 + 2] = v.z; xA[q * 4 + 3] = v.w;
            float4 u = *(const float4*)(&xs[(t + 128) * LSTR + q * 4]);
            xB[q * 4] = u.x; xB[q * 4 + 1] = u.y; xB[q * 4 + 2] = u.z; xB[q * 4 + 3] = u.w;
        }
        // ---- fully-unrolled FMA, weight reused for both rows ----
        const float* wk = w + kt * 32 * HID;
#pragma unroll
        for (int k = 0; k < 32; ++k) {
            float f0 = xA[k], f1 = xB[k];
            const float* wr = wk + k * HID;
#pragma unroll
            for (int j = 0; j < HID; ++j) {
                float wv = wr[j];
                a0[j] = __builtin_fmaf(f0, wv, a0[j]);
                a1[j] = __builtin_fmaf(f1, wv, a1[j]);
            }
        }
    }

    // ---- store via LDS, full-line coalesced ----
    __syncthreads();
#pragma unroll
    for (int j = 0; j < HID; j += 4) {
        *(float4*)(&xs[t * LSTR + j]) = make_float4(a0[j], a0[j + 1], a0[j + 2], a0[j + 3]);
        *(float4*)(&xs[(t + 128) * LSTR + j]) = make_float4(a1[j], a1[j + 1], a1[j + 2], a1[j + 3]);
    }
    __syncthreads();
#pragma unroll
    for (int sub = 0; sub < 16; ++sub) {
        int f = sub * 128 + t;
        int r = f >> 3, k4 = f & 7;
        long gr = row0 + r;
        if (gr < n)
            *(float4*)(out + gr * HID + k4 * 4) = *(const float4*)(&xs[r * LSTR + k4 * 4]);
    }
}

// ================= L2/L3 dense pre-transform (column-major input) ===========
// Input xT is [32][NND] column-major (written by k_agg's CM store). Thread i
// owns rows i and i+NHALF: all 64 feature loads are perfectly coalesced and
// independent; no LDS, no barriers. Output row-major (wave covers 64
// consecutive rows -> full-line write coverage, proven no amplification).
__global__ __launch_bounds__(256, 2)
void k_preCM(const float* __restrict__ xT, const float* __restrict__ w,
             const float* __restrict__ b, float* __restrict__ out) {
    int i = blockIdx.x * 256 + threadIdx.x;
    if (i >= NHALF) return;
    float a0[HID], a1[HID];
#pragma unroll
    for (int j = 0; j < HID; ++j) { float bv = b ? b[j] : 0.0f; a0[j] = bv; a1[j] = bv; }
#pragma unroll
    for (int k = 0; k < 32; ++k) {
        float f0 = xT[(size_t)k * NND + i];
        float f1 = xT[(size_t)k * NND + i + NHALF];
        const float* wr = w + k * HID;
#pragma unroll
        for (int j = 0; j < HID; ++j) {
            float wv = wr[j];
            a0[j] = __builtin_fmaf(f0, wv, a0[j]);
            a1[j] = __builtin_fmaf(f1, wv, a1[j]);
        }
    }
    float* o0 = out + (size_t)i * HID;
    float* o1 = out + (size_t)(i + NHALF) * HID;
#pragma unroll
    for (int j = 0; j < HID; j += 4) {
        *(float4*)(o0 + j) = make_float4(a0[j], a0[j + 1], a0[j + 2], a0[j + 3]);
        *(float4*)(o1 + j) = make_float4(a1[j], a1[j + 1], a1[j + 2], a1[j + 3]);
    }
}

// ================= shuffle-free SAGE aggregation ============================
// 8 lanes per dst node, float4 row slices, 8-deep clamped gather unroll.
// CM=true: store h column-major [32][NND] (feeds k_preCM).
// FINAL=true: apply 32->2 classifier into d_out.
template<bool CM, bool FINAL>
__global__ __launch_bounds__(256)
void k_agg(const int* __restrict__ rp, const int* __restrict__ col,
           const float* __restrict__ preL, const float* __restrict__ preR,
           float* __restrict__ y,
           const float* __restrict__ wo, const float* __restrict__ bo, int n) {
    int t = blockIdx.x * 256 + threadIdx.x;
    int g = t >> 3;     // node
    int u = t & 7;      // float4 slot within row
    if (g >= n) return;
    int p0 = rp[g], p1 = rp[g + 1];

    float ax = 0.0f, ay = 0.0f, az = 0.0f, aw = 0.0f;
    for (int k = p0; k < p1; k += 8) {
        int last = p1 - 1;
        int idx[8];
#pragma unroll
        for (int q = 0; q < 8; ++q) {
            int e = k + q;
            idx[q] = col[e < p1 ? e : last];
        }
        float4 v[8];
#pragma unroll
        for (int q = 0; q < 8; ++q)
            v[q] = *(const float4*)(preL + (size_t)idx[q] * HID + u * 4);
#pragma unroll
        for (int q = 0; q < 8; ++q) {
            if (k + q < p1) {
                ax += v[q].x; ay += v[q].y; az += v[q].z; aw += v[q].w;
            }
        }
    }
    float inv = 1.0f / fmaxf((float)(p1 - p0), 1.0f);
    float4 r = *(const float4*)(preR + (size_t)g * HID + u * 4);
    float4 h;
    h.x = fmaxf(__builtin_fmaf(ax, inv, r.x), 0.0f);
    h.y = fmaxf(__builtin_fmaf(ay, inv, r.y), 0.0f);
    h.z = fmaxf(__builtin_fmaf(az, inv, r.z), 0.0f);
    h.w = fmaxf(__builtin_fmaf(aw, inv, r.w), 0.0f);

    if (FINAL) {
        int j = u * 4;
        float o0 = h.x * wo[(j + 0) * 2 + 0] + h.y * wo[(j + 1) * 2 + 0]
                 + h.z * wo[(j + 2) * 2 + 0] + h.w * wo[(j + 3) * 2 + 0];
        float o1 = h.x * wo[(j + 0) * 2 + 1] + h.y * wo[(j + 1) * 2 + 1]
                 + h.z * wo[(j + 2) * 2 + 1] + h.w * wo[(j + 3) * 2 + 1];
#pragma unroll
        for (int m = 4; m >= 1; m >>= 1) {
            o0 += __shfl_xor(o0, m, 8);
            o1 += __shfl_xor(o1, m, 8);
        }
        if (u == 0) {
            y[(size_t)g * 2 + 0] = o0 + bo[0];
            y[(size_t)g * 2 + 1] = o1 + bo[1];
        }
    } else if (CM) {
        int c = u * 4;
        y[(size_t)(c + 0) * NND + g] = h.x;
        y[(size_t)(c + 1) * NND + g] = h.y;
        y[(size_t)(c + 2) * NND + g] = h.z;
        y[(size_t)(c + 3) * NND + g] = h.w;
    } else {
        *(float4*)(y + (size_t)g * HID + u * 4) = h;
    }
}

// ============================================================================

extern "C" void kernel_launch(void* const* d_in, const int* in_sizes, int n_in,
                              void* d_out, int out_size, void* d_ws, size_t ws_size,
                              hipStream_t stream) {
    const float* x_addr  = (const float*)d_in[0];
    const float* x_tx    = (const float*)d_in[1];
    const int*   ei_at   = (const int*)d_in[2];
    const int*   ei_ta   = (const int*)d_in[3];
    const float* w1_tx_l = (const float*)d_in[4];  const float* b1_tx = (const float*)d_in[5];
    const float* w1_tx_r = (const float*)d_in[6];
    const float* w1_ad_l = (const float*)d_in[7];  const float* b1_ad = (const float*)d_in[8];
    const float* w1_ad_r = (const float*)d_in[9];
    const float* w2_tx_l = (const float*)d_in[10]; const float* b2_tx = (const float*)d_in[11];
    const float* w2_tx_r = (const float*)d_in[12];
    const float* w2_ad_l = (const float*)d_in[13]; const float* b2_ad = (const float*)d_in[14];
    const float* w2_ad_r = (const float*)d_in[15];
    // d_in[16..18] unused (w3_tx_*)
    const float* w3_ad_l = (const float*)d_in[19]; const float* b3_ad = (const float*)d_in[20];
    const float* w3_ad_r = (const float*)d_in[21];
    const float* w_out   = (const float*)d_in[22]; const float* b_out = (const float*)d_in[23];
    float* out = (float*)d_out;

    // ---- workspace carve (E overlays the build-only eb_* arrays) ----
    char* base = (char*)d_ws;
    int* bcnt   = (int*)base;  base += (size_t)(2 * NB) * 4;
    int* bbase  = (int*)base;  base += (size_t)(2 * (NB + 1)) * 4;
    int* gcur   = (int*)base;  base += (size_t)(2 * NB) * 4;
    int* rp_tx  = (int*)base;  base += (size_t)(NND + 1) * 4;
    int* rp_ad  = (int*)base;  base += (size_t)(NND + 1) * 4;
    int* col_at = (int*)base;  base += (size_t)NEDGE * 4;
    int* col_ta = (int*)base;  base += (size_t)NEDGE * 4;
    base = (char*)(((size_t)base + 255) & ~(size_t)255);
    const size_t SLOT = (size_t)NND * HID;
    float* E = (float*)base;                     // slot E (reuses eb region)
    unsigned* eb_at = (unsigned*)base;           // build-only, dead after k_csrb
    unsigned* eb_ta = eb_at + (size_t)NEDGE;
    float* A = E + SLOT;
    float* B = A + SLOT;
    float* C = B + SLOT;
    float* D = C + SLOT;

    dim3 blk(256);
    dim3 blk128(128);
    int gN  = cdiv_host(NND, 256);                // 1563 (256 rows per k_preS block)
    int gCM = cdiv_host(NHALF, 256);              // 782
    int gG  = cdiv_host((long)NND * 8, 256);      // 12500
    const int GH = 96, GD = 192;

    // ---- bucketed CSR build ----
    hipMemsetAsync(bcnt, 0, (size_t)(2 * NB) * 4, stream);
    k_hist<<<2 * GH, blk, 0, stream>>>(ei_at + NEDGE, ei_ta + NEDGE, bcnt, GH);
    k_scan_nb<<<2, blk, 0, stream>>>(bcnt, bbase, gcur);
    k_dist<<<2 * GD, blk, 0, stream>>>(ei_at, ei_ta, gcur, eb_at, eb_ta, GD);
    k_csrb<<<2 * NB, blk, 0, stream>>>(eb_at, eb_ta, bbase, rp_tx, rp_ad, col_at, col_ta);

    // ---- layer 1: tx = relu(mean_at(x_addr@w1_tx_l) + x_tx@w1_tx_r + b1) ----
    k_preS<FIN><<<gN, blk128, 0, stream>>>(x_addr, w1_tx_l, nullptr, A, NADDR);  // pL-tx
    k_preS<FIN><<<gN, blk128, 0, stream>>>(x_tx, w1_tx_r, b1_tx, D, NTX);        // pR-tx
    k_agg<true, false><<<gG, blk, 0, stream>>>(rp_tx, col_at, A, D, C, nullptr, nullptr, NTX);   // C = TX (CM)
    // ---- layer 1: ad ----
    k_preS<FIN><<<gN, blk128, 0, stream>>>(x_tx, w1_ad_l, nullptr, A, NTX);      // pL-ad
    k_preS<FIN><<<gN, blk128, 0, stream>>>(x_addr, w1_ad_r, b1_ad, D, NADDR);    // pR-ad
    k_agg<true, false><<<gG, blk, 0, stream>>>(rp_ad, col_ta, A, D, B, nullptr, nullptr, NADDR); // B = AD (CM)

    // ---- layer 2 ----
    k_preCM<<<gCM, blk, 0, stream>>>(B, w2_tx_l, nullptr, A);   // A = pL-tx2 (from AD)
    k_preCM<<<gCM, blk, 0, stream>>>(C, w2_tx_r, b2_tx, D);     // D = pR-tx2 (from TX)
    k_preCM<<<gCM, blk, 0, stream>>>(C, w2_ad_l, nullptr, E);   // E = pL-ad2 (from TX; TX dead)
    k_agg<true, false><<<gG, blk, 0, stream>>>(rp_tx, col_at, A, D, C, nullptr, nullptr, NTX);   // C = TX2 (CM)
    k_preCM<<<gCM, blk, 0, stream>>>(B, w2_ad_r, b2_ad, A);     // A = pR-ad2 (from AD; AD dead)
    k_agg<true, false><<<gG, blk, 0, stream>>>(rp_ad, col_ta, E, A, D, nullptr, nullptr, NADDR); // D = AD2 (CM)

    // ---- layer 3 + classifier ----
    k_preCM<<<gCM, blk, 0, stream>>>(C, w3_ad_l, nullptr, A);   // A = pL-ad3 (from TX2)
    k_preCM<<<gCM, blk, 0, stream>>>(D, w3_ad_r, b3_ad, B);     // B = pR-ad3 (from AD2)
    k_agg<false, true><<<gG, blk, 0, stream>>>(rp_ad, col_ta, A, B, out, w_out, b_out, NADDR);
}

// Round 10
// 718.930 us; speedup vs baseline: 1.1289x; 1.1289x over previous
//
#include <hip/hip_runtime.h>

#define NADDR 400000
#define NTX   400000
#define NEDGE 1500000
#define FIN   64
#define HID   32
#define NB    1563        // buckets per node type; 256 nodes per bucket
#define LSTR  36          // LDS row stride (floats): 144 B, 16B-aligned rows
#define NND   400000      // nodes per type
#define NHALF 200000      // NND / 2 (R=2 rows per thread in k_preCM1)

static inline int cdiv_host(long a, int b) { return (int)((a + b - 1) / b); }

// ================= bucketed CSR build (verified round-4 chain) ==============

__global__ void k_hist(const int* __restrict__ at_dst, const int* __restrict__ ta_dst,
                       int* __restrict__ bcnt /*[2*NB]*/, int GH) {
    __shared__ int h[NB];
    bool wh = blockIdx.x >= GH;
    int blk = blockIdx.x - (wh ? GH : 0);
    const int* dst = wh ? ta_dst : at_dst;
    for (int i = threadIdx.x; i < NB; i += 256) h[i] = 0;
    __syncthreads();
    for (long e = (long)blk * 256 + threadIdx.x; e < NEDGE; e += (long)GH * 256)
        atomicAdd(&h[dst[e] >> 8], 1);
    __syncthreads();
    int* g = bcnt + (wh ? NB : 0);
    for (int i = threadIdx.x; i < NB; i += 256) {
        int v = h[i];
        if (v) atomicAdd(&g[i], v);
    }
}

__global__ void k_scan_nb(const int* __restrict__ bcnt, int* __restrict__ bbase,
                          int* __restrict__ gcur) {
    __shared__ int sm[256];
    __shared__ int carry;
    int w = blockIdx.x;
    int t = threadIdx.x;
    if (t == 0) carry = 0;
    __syncthreads();
    for (int base = 0; base < NB; base += 256) {
        int i = base + t;
        int v = (i < NB) ? bcnt[w * NB + i] : 0;
        sm[t] = v;
        __syncthreads();
        for (int off = 1; off < 256; off <<= 1) {
            int x = (t >= off) ? sm[t - off] : 0;
            __syncthreads();
            sm[t] += x;
            __syncthreads();
        }
        int excl = sm[t] - v + carry;
        if (i < NB) { bbase[w * (NB + 1) + i] = excl; gcur[w * NB + i] = excl; }
        int tot = sm[255];
        __syncthreads();
        if (t == 0) carry += tot;
        __syncthreads();
    }
    if (t == 0) bbase[w * (NB + 1) + NB] = NEDGE;
}

__global__ void k_dist(const int* __restrict__ ei_at, const int* __restrict__ ei_ta,
                       int* __restrict__ gcur, unsigned* __restrict__ eb_at,
                       unsigned* __restrict__ eb_ta, int GD) {
    __shared__ int h[NB];
    __shared__ int bs[NB];
    bool wh = blockIdx.x >= GD;
    int blk = blockIdx.x - (wh ? GD : 0);
    const int* ei = wh ? ei_ta : ei_at;
    unsigned* eb = wh ? eb_ta : eb_at;
    for (int i = threadIdx.x; i < NB; i += 256) h[i] = 0;
    __syncthreads();
    long e0 = (long)blk * 256 + threadIdx.x;
    long stride = (long)GD * 256;
    for (long e = e0; e < NEDGE; e += stride)
        atomicAdd(&h[ei[NEDGE + e] >> 8], 1);
    __syncthreads();
    int* gc = gcur + (wh ? NB : 0);
    for (int i = threadIdx.x; i < NB; i += 256) {
        int c = h[i];
        bs[i] = c ? atomicAdd(&gc[i], c) : 0;
        h[i] = 0;
    }
    __syncthreads();
    for (long e = e0; e < NEDGE; e += stride) {
        int d = ei[NEDGE + e];
        int s = ei[e];
        int b = d >> 8;
        int r = atomicAdd(&h[b], 1);
        eb[bs[b] + r] = ((unsigned)s << 8) | (unsigned)(d & 255);
    }
}

__global__ void k_csrb(const unsigned* __restrict__ eb_at, const unsigned* __restrict__ eb_ta,
                       const int* __restrict__ bbase,
                       int* __restrict__ rp_tx, int* __restrict__ rp_ad,
                       int* __restrict__ col_at, int* __restrict__ col_ta) {
    __shared__ int deg[256];
    __shared__ int cur[256];
    __shared__ int sm[256];
    bool wh = blockIdx.x >= NB;
    int b = blockIdx.x - (wh ? NB : 0);
    const unsigned* eb = wh ? eb_ta : eb_at;
    int* rp  = wh ? rp_ad  : rp_tx;
    int* col = wh ? col_ta : col_at;
    const int* bb = bbase + (wh ? (NB + 1) : 0);
    int e0 = bb[b], e1 = bb[b + 1];
    int t = threadIdx.x;
    deg[t] = 0;
    __syncthreads();
    for (int e = e0 + t; e < e1; e += 256)
        atomicAdd(&deg[eb[e] & 255], 1);
    __syncthreads();
    int v = deg[t];
    sm[t] = v;
    __syncthreads();
    for (int off = 1; off < 256; off <<= 1) {
        int x = (t >= off) ? sm[t - off] : 0;
        __syncthreads();
        sm[t] += x;
        __syncthreads();
    }
    int excl = sm[t] - v;
    int node = b * 256 + t;
    if (node < NND) rp[node] = e0 + excl;
    cur[t] = e0 + excl;
    __syncthreads();
    for (int e = e0 + t; e < e1; e += 256) {
        unsigned p = eb[e];
        int idx = atomicAdd(&cur[p & 255], 1);
        col[idx] = (int)(p >> 8);
    }
    if (t == 0 && b == 0) rp[NND] = NEDGE;
}

// ================= L1 dual pre-transform (row-major input) ==================
// 128 threads / 128 rows per block -> LDS 18.4 KB -> 8 blocks/CU for
// inter-block latency overlap across barrier phases. Each thread owns one row
// (register-resident), computes BOTH outputs (x read once): outa = x@wa,
// outb = x@wb + bb. Staging and stores fully coalesced (full-line).
__global__ __launch_bounds__(128)
void k_preS2(const float* __restrict__ x,
             const float* __restrict__ wa, float* __restrict__ outa,
             const float* __restrict__ wb, const float* __restrict__ bb,
             float* __restrict__ outb, int n) {
    __shared__ alignas(16) float xs[128 * LSTR];   // 18432 B
    int t = threadIdx.x;
    long row0 = (long)blockIdx.x * 128;

    float aa[HID], ab[HID];
#pragma unroll
    for (int j = 0; j < HID; ++j) { aa[j] = 0.0f; ab[j] = bb[j]; }

    for (int kt = 0; kt < FIN / 32; ++kt) {
        if (kt) __syncthreads();
        // stage 128 rows x 32 feats (1024 float4, 8 per thread), coalesced
#pragma unroll
        for (int sub = 0; sub < 8; ++sub) {
            int f = sub * 128 + t;
            int r = f >> 3, k4 = f & 7;
            long gr = row0 + r;
            if (gr >= n) gr = n - 1;
            *(float4*)(&xs[r * LSTR + k4 * 4]) =
                *(const float4*)(x + gr * FIN + kt * 32 + k4 * 4);
        }
        __syncthreads();
        // preload this thread's row
        float xr[32];
#pragma unroll
        for (int q = 0; q < 8; ++q) {
            float4 v = *(const float4*)(&xs[t * LSTR + q * 4]);
            xr[q * 4] = v.x; xr[q * 4 + 1] = v.y; xr[q * 4 + 2] = v.z; xr[q * 4 + 3] = v.w;
        }
        // fully-unrolled FMA for both outputs
        const float* wka = wa + kt * 32 * HID;
        const float* wkb = wb + kt * 32 * HID;
#pragma unroll
        for (int k = 0; k < 32; ++k) {
            float xk = xr[k];
            const float* ra = wka + k * HID;
            const float* rb = wkb + k * HID;
#pragma unroll
            for (int j = 0; j < HID; ++j) {
                aa[j] = __builtin_fmaf(xk, ra[j], aa[j]);
                ab[j] = __builtin_fmaf(xk, rb[j], ab[j]);
            }
        }
    }

    // store outa then outb via LDS, full-line coalesced
    __syncthreads();
#pragma unroll
    for (int j = 0; j < HID; j += 4)
        *(float4*)(&xs[t * LSTR + j]) = make_float4(aa[j], aa[j + 1], aa[j + 2], aa[j + 3]);
    __syncthreads();
#pragma unroll
    for (int sub = 0; sub < 8; ++sub) {
        int f = sub * 128 + t;
        int r = f >> 3, k4 = f & 7;
        long gr = row0 + r;
        if (gr < n)
            *(float4*)(outa + gr * HID + k4 * 4) = *(const float4*)(&xs[r * LSTR + k4 * 4]);
    }
    __syncthreads();
#pragma unroll
    for (int j = 0; j < HID; j += 4)
        *(float4*)(&xs[t * LSTR + j]) = make_float4(ab[j], ab[j + 1], ab[j + 2], ab[j + 3]);
    __syncthreads();
#pragma unroll
    for (int sub = 0; sub < 8; ++sub) {
        int f = sub * 128 + t;
        int r = f >> 3, k4 = f & 7;
        long gr = row0 + r;
        if (gr < n)
            *(float4*)(outb + gr * HID + k4 * 4) = *(const float4*)(&xs[r * LSTR + k4 * 4]);
    }
}

// ================= L2 dual pre-transform (column-major input) ===============
// xT is [32][NND]. Thread i owns row i: 32 independent perfectly-coalesced
// loads, no LDS, no barriers. Computes both outputs (input read once).
__global__ __launch_bounds__(256)
void k_preCMD(const float* __restrict__ xT,
              const float* __restrict__ wa, float* __restrict__ outa,
              const float* __restrict__ wb, const float* __restrict__ bb,
              float* __restrict__ outb) {
    int i = blockIdx.x * 256 + threadIdx.x;
    if (i >= NND) return;
    float aa[HID], ab[HID];
#pragma unroll
    for (int j = 0; j < HID; ++j) { aa[j] = 0.0f; ab[j] = bb[j]; }
#pragma unroll
    for (int k = 0; k < 32; ++k) {
        float f = xT[(size_t)k * NND + i];
        const float* ra = wa + k * HID;
        const float* rb = wb + k * HID;
#pragma unroll
        for (int j = 0; j < HID; ++j) {
            aa[j] = __builtin_fmaf(f, ra[j], aa[j]);
            ab[j] = __builtin_fmaf(f, rb[j], ab[j]);
        }
    }
    float* oa = outa + (size_t)i * HID;
    float* ob = outb + (size_t)i * HID;
#pragma unroll
    for (int j = 0; j < HID; j += 4) {
        *(float4*)(oa + j) = make_float4(aa[j], aa[j + 1], aa[j + 2], aa[j + 3]);
        *(float4*)(ob + j) = make_float4(ab[j], ab[j + 1], ab[j + 2], ab[j + 3]);
    }
}

// ================= L3 single pre-transform (column-major input, R=2) ========
__global__ __launch_bounds__(256, 2)
void k_preCM1(const float* __restrict__ xT, const float* __restrict__ w,
              const float* __restrict__ b, float* __restrict__ out) {
    int i = blockIdx.x * 256 + threadIdx.x;
    if (i >= NHALF) return;
    float a0[HID], a1[HID];
#pragma unroll
    for (int j = 0; j < HID; ++j) { float bv = b ? b[j] : 0.0f; a0[j] = bv; a1[j] = bv; }
#pragma unroll
    for (int k = 0; k < 32; ++k) {
        float f0 = xT[(size_t)k * NND + i];
        float f1 = xT[(size_t)k * NND + i + NHALF];
        const float* wr = w + k * HID;
#pragma unroll
        for (int j = 0; j < HID; ++j) {
            float wv = wr[j];
            a0[j] = __builtin_fmaf(f0, wv, a0[j]);
            a1[j] = __builtin_fmaf(f1, wv, a1[j]);
        }
    }
    float* o0 = out + (size_t)i * HID;
    float* o1 = out + (size_t)(i + NHALF) * HID;
#pragma unroll
    for (int j = 0; j < HID; j += 4) {
        *(float4*)(o0 + j) = make_float4(a0[j], a0[j + 1], a0[j + 2], a0[j + 3]);
        *(float4*)(o1 + j) = make_float4(a1[j], a1[j + 1], a1[j + 2], a1[j + 3]);
    }
}

// ================= shuffle-free SAGE aggregation ============================
// 8 lanes per dst node, float4 row slices, 8-deep clamped gather unroll.
// CM=true: store result column-major [32][NND] (feeds k_preCMD/k_preCM1).
// FINAL=true: apply 32->2 classifier into d_out.
template<bool CM, bool FINAL>
__global__ __launch_bounds__(256)
void k_agg(const int* __restrict__ rp, const int* __restrict__ col,
           const float* __restrict__ preL, const float* __restrict__ preR,
           float* __restrict__ y,
           const float* __restrict__ wo, const float* __restrict__ bo, int n) {
    int t = blockIdx.x * 256 + threadIdx.x;
    int g = t >> 3;     // node
    int u = t & 7;      // float4 slot within row
    if (g >= n) return;
    int p0 = rp[g], p1 = rp[g + 1];

    float ax = 0.0f, ay = 0.0f, az = 0.0f, aw = 0.0f;
    for (int k = p0; k < p1; k += 8) {
        int last = p1 - 1;
        int idx[8];
#pragma unroll
        for (int q = 0; q < 8; ++q) {
            int e = k + q;
            idx[q] = col[e < p1 ? e : last];
        }
        float4 v[8];
#pragma unroll
        for (int q = 0; q < 8; ++q)
            v[q] = *(const float4*)(preL + (size_t)idx[q] * HID + u * 4);
#pragma unroll
        for (int q = 0; q < 8; ++q) {
            if (k + q < p1) {
                ax += v[q].x; ay += v[q].y; az += v[q].z; aw += v[q].w;
            }
        }
    }
    float inv = 1.0f / fmaxf((float)(p1 - p0), 1.0f);
    float4 r = *(const float4*)(preR + (size_t)g * HID + u * 4);
    float4 h;
    h.x = fmaxf(__builtin_fmaf(ax, inv, r.x), 0.0f);
    h.y = fmaxf(__builtin_fmaf(ay, inv, r.y), 0.0f);
    h.z = fmaxf(__builtin_fmaf(az, inv, r.z), 0.0f);
    h.w = fmaxf(__builtin_fmaf(aw, inv, r.w), 0.0f);

    if (FINAL) {
        int j = u * 4;
        float o0 = h.x * wo[(j + 0) * 2 + 0] + h.y * wo[(j + 1) * 2 + 0]
                 + h.z * wo[(j + 2) * 2 + 0] + h.w * wo[(j + 3) * 2 + 0];
        float o1 = h.x * wo[(j + 0) * 2 + 1] + h.y * wo[(j + 1) * 2 + 1]
                 + h.z * wo[(j + 2) * 2 + 1] + h.w * wo[(j + 3) * 2 + 1];
#pragma unroll
        for (int m = 4; m >= 1; m >>= 1) {
            o0 += __shfl_xor(o0, m, 8);
            o1 += __shfl_xor(o1, m, 8);
        }
        if (u == 0) {
            y[(size_t)g * 2 + 0] = o0 + bo[0];
            y[(size_t)g * 2 + 1] = o1 + bo[1];
        }
    } else if (CM) {
        int c = u * 4;
        y[(size_t)(c + 0) * NND + g] = h.x;
        y[(size_t)(c + 1) * NND + g] = h.y;
        y[(size_t)(c + 2) * NND + g] = h.z;
        y[(size_t)(c + 3) * NND + g] = h.w;
    } else {
        *(float4*)(y + (size_t)g * HID + u * 4) = h;
    }
}

// ============================================================================

extern "C" void kernel_launch(void* const* d_in, const int* in_sizes, int n_in,
                              void* d_out, int out_size, void* d_ws, size_t ws_size,
                              hipStream_t stream) {
    const float* x_addr  = (const float*)d_in[0];
    const float* x_tx    = (const float*)d_in[1];
    const int*   ei_at   = (const int*)d_in[2];
    const int*   ei_ta   = (const int*)d_in[3];
    const float* w1_tx_l = (const float*)d_in[4];  const float* b1_tx = (const float*)d_in[5];
    const float* w1_tx_r = (const float*)d_in[6];
    const float* w1_ad_l = (const float*)d_in[7];  const float* b1_ad = (const float*)d_in[8];
    const float* w1_ad_r = (const float*)d_in[9];
    const float* w2_tx_l = (const float*)d_in[10]; const float* b2_tx = (const float*)d_in[11];
    const float* w2_tx_r = (const float*)d_in[12];
    const float* w2_ad_l = (const float*)d_in[13]; const float* b2_ad = (const float*)d_in[14];
    const float* w2_ad_r = (const float*)d_in[15];
    // d_in[16..18] unused (w3_tx_*)
    const float* w3_ad_l = (const float*)d_in[19]; const float* b3_ad = (const float*)d_in[20];
    const float* w3_ad_r = (const float*)d_in[21];
    const float* w_out   = (const float*)d_in[22]; const float* b_out = (const float*)d_in[23];
    float* out = (float*)d_out;

    // ---- workspace carve (round-9-proven footprint; E overlays eb_*) ----
    char* base = (char*)d_ws;
    int* bcnt   = (int*)base;  base += (size_t)(2 * NB) * 4;
    int* bbase  = (int*)base;  base += (size_t)(2 * (NB + 1)) * 4;
    int* gcur   = (int*)base;  base += (size_t)(2 * NB) * 4;
    int* rp_tx  = (int*)base;  base += (size_t)(NND + 1) * 4;
    int* rp_ad  = (int*)base;  base += (size_t)(NND + 1) * 4;
    int* col_at = (int*)base;  base += (size_t)NEDGE * 4;
    int* col_ta = (int*)base;  base += (size_t)NEDGE * 4;
    base = (char*)(((size_t)base + 255) & ~(size_t)255);
    const size_t SLOT = (size_t)NND * HID;
    float* E = (float*)base;                     // overlays eb region (dead after build)
    unsigned* eb_at = (unsigned*)base;           // build-only
    unsigned* eb_ta = eb_at + (size_t)NEDGE;
    float* A = E + SLOT;
    float* B = A + SLOT;
    float* C = B + SLOT;
    float* D = C + SLOT;

    dim3 blk(256);
    dim3 blk128(128);
    int gS  = cdiv_host(NND, 128);                // 3125 (k_preS2)
    int gD  = cdiv_host(NND, 256);                // 1563 (k_preCMD)
    int gCM = cdiv_host(NHALF, 256);              // 782  (k_preCM1)
    int gG  = cdiv_host((long)NND * 8, 256);      // 12500
    const int GH = 96, GD = 192;

    // ---- bucketed CSR build ----
    hipMemsetAsync(bcnt, 0, (size_t)(2 * NB) * 4, stream);
    k_hist<<<2 * GH, blk, 0, stream>>>(ei_at + NEDGE, ei_ta + NEDGE, bcnt, GH);
    k_scan_nb<<<2, blk, 0, stream>>>(bcnt, bbase, gcur);
    k_dist<<<2 * GD, blk, 0, stream>>>(ei_at, ei_ta, gcur, eb_at, eb_ta, GD);
    k_csrb<<<2 * NB, blk, 0, stream>>>(eb_at, eb_ta, bbase, rp_tx, rp_ad, col_at, col_ta);

    // ---- layer 1 pre-transforms (dual: each x read once) ----
    // A = x_addr@w1_tx_l (pL-tx)   B = x_addr@w1_ad_r + b1_ad (pR-ad)
    k_preS2<<<gS, blk128, 0, stream>>>(x_addr, w1_tx_l, A, w1_ad_r, b1_ad, B, NADDR);
    // C = x_tx@w1_ad_l (pL-ad)     D = x_tx@w1_tx_r + b1_tx (pR-tx)
    k_preS2<<<gS, blk128, 0, stream>>>(x_tx, w1_ad_l, C, w1_tx_r, b1_tx, D, NTX);
    // ---- layer 1 aggregations (CM outputs) ----
    k_agg<true, false><<<gG, blk, 0, stream>>>(rp_tx, col_at, A, D, E, nullptr, nullptr, NTX);   // E = TX (CM); A,D dead
    k_agg<true, false><<<gG, blk, 0, stream>>>(rp_ad, col_ta, C, B, A, nullptr, nullptr, NADDR); // A = AD (CM); C,B dead

    // ---- layer 2 pre-transforms (dual CM: each hidden state read once) ----
    // from AD(A): B = AD@w2_tx_l (pL-tx2)   C = AD@w2_ad_r + b2_ad (pR-ad2)
    k_preCMD<<<gD, blk, 0, stream>>>(A, w2_tx_l, B, w2_ad_r, b2_ad, C);  // A dead after
    // from TX(E): D = TX@w2_ad_l (pL-ad2)   A = TX@w2_tx_r + b2_tx (pR-tx2)
    k_preCMD<<<gD, blk, 0, stream>>>(E, w2_ad_l, D, w2_tx_r, b2_tx, A);  // E dead after
    // ---- layer 2 aggregations ----
    k_agg<true, false><<<gG, blk, 0, stream>>>(rp_tx, col_at, B, A, E, nullptr, nullptr, NTX);   // E = TX2 (CM); B,A dead
    k_agg<true, false><<<gG, blk, 0, stream>>>(rp_ad, col_ta, D, C, A, nullptr, nullptr, NADDR); // A = AD2 (CM); D,C dead

    // ---- layer 3 pre-transforms + final aggregation/classifier ----
    k_preCM1<<<gCM, blk, 0, stream>>>(E, w3_ad_l, nullptr, B);   // B = pL-ad3 (from TX2)
    k_preCM1<<<gCM, blk, 0, stream>>>(A, w3_ad_r, b3_ad, C);     // C = pR-ad3 (from AD2)
    k_agg<false, true><<<gG, blk, 0, stream>>>(rp_ad, col_ta, B, C, out, w_out, b_out, NADDR);
}

// Round 11
// 672.592 us; speedup vs baseline: 1.2066x; 1.0689x over previous
//
#include <hip/hip_runtime.h>

#define NADDR 400000
#define NTX   400000
#define NEDGE 1500000
#define FIN   64
#define HID   32
#define NB    1563        // buckets per node type; 256 nodes per bucket
#define LSTR  36          // LDS row stride (floats) in k_preS2
#define HSTR  36          // LDS row stride (floats) in k_aggE (144B, 16B-aligned)
#define NND   400000

static inline int cdiv_host(long a, int b) { return (int)((a + b - 1) / b); }

// ================= bucketed CSR build (verified round-4 chain) ==============

__global__ void k_hist(const int* __restrict__ at_dst, const int* __restrict__ ta_dst,
                       int* __restrict__ bcnt /*[2*NB]*/, int GH) {
    __shared__ int h[NB];
    bool wh = blockIdx.x >= GH;
    int blk = blockIdx.x - (wh ? GH : 0);
    const int* dst = wh ? ta_dst : at_dst;
    for (int i = threadIdx.x; i < NB; i += 256) h[i] = 0;
    __syncthreads();
    for (long e = (long)blk * 256 + threadIdx.x; e < NEDGE; e += (long)GH * 256)
        atomicAdd(&h[dst[e] >> 8], 1);
    __syncthreads();
    int* g = bcnt + (wh ? NB : 0);
    for (int i = threadIdx.x; i < NB; i += 256) {
        int v = h[i];
        if (v) atomicAdd(&g[i], v);
    }
}

__global__ void k_scan_nb(const int* __restrict__ bcnt, int* __restrict__ bbase,
                          int* __restrict__ gcur) {
    __shared__ int sm[256];
    __shared__ int carry;
    int w = blockIdx.x;
    int t = threadIdx.x;
    if (t == 0) carry = 0;
    __syncthreads();
    for (int base = 0; base < NB; base += 256) {
        int i = base + t;
        int v = (i < NB) ? bcnt[w * NB + i] : 0;
        sm[t] = v;
        __syncthreads();
        for (int off = 1; off < 256; off <<= 1) {
            int x = (t >= off) ? sm[t - off] : 0;
            __syncthreads();
            sm[t] += x;
            __syncthreads();
        }
        int excl = sm[t] - v + carry;
        if (i < NB) { bbase[w * (NB + 1) + i] = excl; gcur[w * NB + i] = excl; }
        int tot = sm[255];
        __syncthreads();
        if (t == 0) carry += tot;
        __syncthreads();
    }
    if (t == 0) bbase[w * (NB + 1) + NB] = NEDGE;
}

__global__ void k_dist(const int* __restrict__ ei_at, const int* __restrict__ ei_ta,
                       int* __restrict__ gcur, unsigned* __restrict__ eb_at,
                       unsigned* __restrict__ eb_ta, int GD) {
    __shared__ int h[NB];
    __shared__ int bs[NB];
    bool wh = blockIdx.x >= GD;
    int blk = blockIdx.x - (wh ? GD : 0);
    const int* ei = wh ? ei_ta : ei_at;
    unsigned* eb = wh ? eb_ta : eb_at;
    for (int i = threadIdx.x; i < NB; i += 256) h[i] = 0;
    __syncthreads();
    long e0 = (long)blk * 256 + threadIdx.x;
    long stride = (long)GD * 256;
    for (long e = e0; e < NEDGE; e += stride)
        atomicAdd(&h[ei[NEDGE + e] >> 8], 1);
    __syncthreads();
    int* gc = gcur + (wh ? NB : 0);
    for (int i = threadIdx.x; i < NB; i += 256) {
        int c = h[i];
        bs[i] = c ? atomicAdd(&gc[i], c) : 0;
        h[i] = 0;
    }
    __syncthreads();
    for (long e = e0; e < NEDGE; e += stride) {
        int d = ei[NEDGE + e];
        int s = ei[e];
        int b = d >> 8;
        int r = atomicAdd(&h[b], 1);
        eb[bs[b] + r] = ((unsigned)s << 8) | (unsigned)(d & 255);
    }
}

__global__ void k_csrb(const unsigned* __restrict__ eb_at, const unsigned* __restrict__ eb_ta,
                       const int* __restrict__ bbase,
                       int* __restrict__ rp_tx, int* __restrict__ rp_ad,
                       int* __restrict__ col_at, int* __restrict__ col_ta) {
    __shared__ int deg[256];
    __shared__ int cur[256];
    __shared__ int sm[256];
    bool wh = blockIdx.x >= NB;
    int b = blockIdx.x - (wh ? NB : 0);
    const unsigned* eb = wh ? eb_ta : eb_at;
    int* rp  = wh ? rp_ad  : rp_tx;
    int* col = wh ? col_ta : col_at;
    const int* bb = bbase + (wh ? (NB + 1) : 0);
    int e0 = bb[b], e1 = bb[b + 1];
    int t = threadIdx.x;
    deg[t] = 0;
    __syncthreads();
    for (int e = e0 + t; e < e1; e += 256)
        atomicAdd(&deg[eb[e] & 255], 1);
    __syncthreads();
    int v = deg[t];
    sm[t] = v;
    __syncthreads();
    for (int off = 1; off < 256; off <<= 1) {
        int x = (t >= off) ? sm[t - off] : 0;
        __syncthreads();
        sm[t] += x;
        __syncthreads();
    }
    int excl = sm[t] - v;
    int node = b * 256 + t;
    if (node < NND) rp[node] = e0 + excl;
    cur[t] = e0 + excl;
    __syncthreads();
    for (int e = e0 + t; e < e1; e += 256) {
        unsigned p = eb[e];
        int idx = atomicAdd(&cur[p & 255], 1);
        col[idx] = (int)(p >> 8);
    }
    if (t == 0 && b == 0) rp[NND] = NEDGE;
}

// ================= L1 dual pre-transform (round-10 proven) ==================
__global__ __launch_bounds__(128)
void k_preS2(const float* __restrict__ x,
             const float* __restrict__ wa, float* __restrict__ outa,
             const float* __restrict__ wb, const float* __restrict__ bb,
             float* __restrict__ outb, int n) {
    __shared__ alignas(16) float xs[128 * LSTR];   // 18432 B
    int t = threadIdx.x;
    long row0 = (long)blockIdx.x * 128;

    float aa[HID], ab[HID];
#pragma unroll
    for (int j = 0; j < HID; ++j) { aa[j] = 0.0f; ab[j] = bb[j]; }

    for (int kt = 0; kt < FIN / 32; ++kt) {
        if (kt) __syncthreads();
#pragma unroll
        for (int sub = 0; sub < 8; ++sub) {
            int f = sub * 128 + t;
            int r = f >> 3, k4 = f & 7;
            long gr = row0 + r;
            if (gr >= n) gr = n - 1;
            *(float4*)(&xs[r * LSTR + k4 * 4]) =
                *(const float4*)(x + gr * FIN + kt * 32 + k4 * 4);
        }
        __syncthreads();
        float xr[32];
#pragma unroll
        for (int q = 0; q < 8; ++q) {
            float4 v = *(const float4*)(&xs[t * LSTR + q * 4]);
            xr[q * 4] = v.x; xr[q * 4 + 1] = v.y; xr[q * 4 + 2] = v.z; xr[q * 4 + 3] = v.w;
        }
        const float* wka = wa + kt * 32 * HID;
        const float* wkb = wb + kt * 32 * HID;
#pragma unroll
        for (int k = 0; k < 32; ++k) {
            float xk = xr[k];
            const float* ra = wka + k * HID;
            const float* rb = wkb + k * HID;
#pragma unroll
            for (int j = 0; j < HID; ++j) {
                aa[j] = __builtin_fmaf(xk, ra[j], aa[j]);
                ab[j] = __builtin_fmaf(xk, rb[j], ab[j]);
            }
        }
    }

    __syncthreads();
#pragma unroll
    for (int j = 0; j < HID; j += 4)
        *(float4*)(&xs[t * LSTR + j]) = make_float4(aa[j], aa[j + 1], aa[j + 2], aa[j + 3]);
    __syncthreads();
#pragma unroll
    for (int sub = 0; sub < 8; ++sub) {
        int f = sub * 128 + t;
        int r = f >> 3, k4 = f & 7;
        long gr = row0 + r;
        if (gr < n)
            *(float4*)(outa + gr * HID + k4 * 4) = *(const float4*)(&xs[r * LSTR + k4 * 4]);
    }
    __syncthreads();
#pragma unroll
    for (int j = 0; j < HID; j += 4)
        *(float4*)(&xs[t * LSTR + j]) = make_float4(ab[j], ab[j + 1], ab[j + 2], ab[j + 3]);
    __syncthreads();
#pragma unroll
    for (int sub = 0; sub < 8; ++sub) {
        int f = sub * 128 + t;
        int r = f >> 3, k4 = f & 7;
        long gr = row0 + r;
        if (gr < n)
            *(float4*)(outb + gr * HID + k4 * 4) = *(const float4*)(&xs[r * LSTR + k4 * 4]);
    }
}

// ================= fused SAGE aggregation + dense epilogue ==================
// Block = 256 threads = 256 dst nodes. Phase 1: 8 sub-batches of 32 nodes
// (8 lanes/node) run the proven gather (8-deep clamped unroll) + preR add +
// relu, writing h rows into LDS. Phase 2 (after one barrier): thread t owns
// node row0+t, pulls its h row from LDS into registers, and applies the NEXT
// layer's transform(s) with wave-uniform (scalar-cached) weights, storing
// full coalesced 128B rows.
//   EP=0 (dual):   outA = h@wA (+bA), outB = h@wB + bB
//   EP=1 (single): outA = h@wA (+bA)
//   EP=2 (final):  outA[n,2] = h@wA + bA   (wA is [32,2])
// preR may alias outA/outB: each row is read (pre-barrier) only by its own
// block and written (post-barrier) only by its own block.
template<int EP>
__global__ __launch_bounds__(256)
void k_aggE(const int* __restrict__ rp, const int* __restrict__ col,
            const float* __restrict__ preL, const float* preR,
            const float* __restrict__ wA, const float* __restrict__ bA, float* outA,
            const float* __restrict__ wB, const float* __restrict__ bB, float* outB,
            int n) {
    __shared__ alignas(16) float hh[256 * HSTR];   // 36864 B
    int t = threadIdx.x;
    long row0 = (long)blockIdx.x * 256;
    int u = t & 7;
    int lnb = t >> 3;   // 0..31

    // ---- phase 1: gather + finalize h into LDS (8 batches of 32 nodes) ----
    for (int bi = 0; bi < 8; ++bi) {
        int ln = bi * 32 + lnb;
        long g = row0 + ln;
        if (g < n) {
            int p0 = rp[g], p1 = rp[g + 1];
            float ax = 0.0f, ay = 0.0f, az = 0.0f, aw = 0.0f;
            for (int k = p0; k < p1; k += 8) {
                int last = p1 - 1;
                int idx[8];
#pragma unroll
                for (int q = 0; q < 8; ++q) {
                    int e = k + q;
                    idx[q] = col[e < p1 ? e : last];
                }
                float4 v[8];
#pragma unroll
                for (int q = 0; q < 8; ++q)
                    v[q] = *(const float4*)(preL + (size_t)idx[q] * HID + u * 4);
#pragma unroll
                for (int q = 0; q < 8; ++q) {
                    if (k + q < p1) {
                        ax += v[q].x; ay += v[q].y; az += v[q].z; aw += v[q].w;
                    }
                }
            }
            float inv = 1.0f / fmaxf((float)(p1 - p0), 1.0f);
            float4 r = *(const float4*)(preR + (size_t)g * HID + u * 4);
            float* hp = &hh[ln * HSTR + u * 4];
            hp[0] = fmaxf(__builtin_fmaf(ax, inv, r.x), 0.0f);
            hp[1] = fmaxf(__builtin_fmaf(ay, inv, r.y), 0.0f);
            hp[2] = fmaxf(__builtin_fmaf(az, inv, r.z), 0.0f);
            hp[3] = fmaxf(__builtin_fmaf(aw, inv, r.w), 0.0f);
        }
    }
    __syncthreads();

    // ---- phase 2: dense epilogue, thread t = node row0+t ----
    long gd = row0 + t;
    if (gd >= n) return;
    float rrow[32];
#pragma unroll
    for (int q = 0; q < 8; ++q) {
        float4 v = *(const float4*)(&hh[t * HSTR + q * 4]);
        rrow[q * 4] = v.x; rrow[q * 4 + 1] = v.y;
        rrow[q * 4 + 2] = v.z; rrow[q * 4 + 3] = v.w;
    }

    if (EP == 2) {
        float o0 = bA[0], o1 = bA[1];
#pragma unroll
        for (int k = 0; k < HID; ++k) {
            o0 = __builtin_fmaf(rrow[k], wA[k * 2 + 0], o0);
            o1 = __builtin_fmaf(rrow[k], wA[k * 2 + 1], o1);
        }
        outA[gd * 2 + 0] = o0;
        outA[gd * 2 + 1] = o1;
        return;
    }

    // pass A
    {
        float acc[HID];
#pragma unroll
        for (int j = 0; j < HID; ++j) acc[j] = bA ? bA[j] : 0.0f;
#pragma unroll
        for (int k = 0; k < HID; ++k) {
            float rk = rrow[k];
            const float* wr = wA + k * HID;
#pragma unroll
            for (int j = 0; j < HID; ++j) acc[j] = __builtin_fmaf(rk, wr[j], acc[j]);
        }
        float* o = outA + (size_t)gd * HID;
#pragma unroll
        for (int j = 0; j < HID; j += 4)
            *(float4*)(o + j) = make_float4(acc[j], acc[j + 1], acc[j + 2], acc[j + 3]);
    }
    if (EP == 0) {
        float acc[HID];
#pragma unroll
        for (int j = 0; j < HID; ++j) acc[j] = bB[j];
#pragma unroll
        for (int k = 0; k < HID; ++k) {
            float rk = rrow[k];
            const float* wr = wB + k * HID;
#pragma unroll
            for (int j = 0; j < HID; ++j) acc[j] = __builtin_fmaf(rk, wr[j], acc[j]);
        }
        float* o = outB + (size_t)gd * HID;
#pragma unroll
        for (int j = 0; j < HID; j += 4)
            *(float4*)(o + j) = make_float4(acc[j], acc[j + 1], acc[j + 2], acc[j + 3]);
    }
}

// ============================================================================

extern "C" void kernel_launch(void* const* d_in, const int* in_sizes, int n_in,
                              void* d_out, int out_size, void* d_ws, size_t ws_size,
                              hipStream_t stream) {
    const float* x_addr  = (const float*)d_in[0];
    const float* x_tx    = (const float*)d_in[1];
    const int*   ei_at   = (const int*)d_in[2];
    const int*   ei_ta   = (const int*)d_in[3];
    const float* w1_tx_l = (const float*)d_in[4];  const float* b1_tx = (const float*)d_in[5];
    const float* w1_tx_r = (const float*)d_in[6];
    const float* w1_ad_l = (const float*)d_in[7];  const float* b1_ad = (const float*)d_in[8];
    const float* w1_ad_r = (const float*)d_in[9];
    const float* w2_tx_l = (const float*)d_in[10]; const float* b2_tx = (const float*)d_in[11];
    const float* w2_tx_r = (const float*)d_in[12];
    const float* w2_ad_l = (const float*)d_in[13]; const float* b2_ad = (const float*)d_in[14];
    const float* w2_ad_r = (const float*)d_in[15];
    // d_in[16..18] unused (w3_tx_*)
    const float* w3_ad_l = (const float*)d_in[19]; const float* b3_ad = (const float*)d_in[20];
    const float* w3_ad_r = (const float*)d_in[21];
    const float* w_out   = (const float*)d_in[22]; const float* b_out = (const float*)d_in[23];
    float* out = (float*)d_out;

    // ---- workspace carve (5 slots, round-10-proven footprint) ----
    char* base = (char*)d_ws;
    int* bcnt   = (int*)base;  base += (size_t)(2 * NB) * 4;
    int* bbase  = (int*)base;  base += (size_t)(2 * (NB + 1)) * 4;
    int* gcur   = (int*)base;  base += (size_t)(2 * NB) * 4;
    int* rp_tx  = (int*)base;  base += (size_t)(NND + 1) * 4;
    int* rp_ad  = (int*)base;  base += (size_t)(NND + 1) * 4;
    int* col_at = (int*)base;  base += (size_t)NEDGE * 4;
    int* col_ta = (int*)base;  base += (size_t)NEDGE * 4;
    base = (char*)(((size_t)base + 255) & ~(size_t)255);
    const size_t SLOT = (size_t)NND * HID;
    float* SE = (float*)base;                    // overlays eb region (dead after build)
    unsigned* eb_at = (unsigned*)base;           // build-only
    unsigned* eb_ta = eb_at + (size_t)NEDGE;
    float* SA = SE + SLOT;
    float* SB = SA + SLOT;
    float* SC = SB + SLOT;
    float* SD = SC + SLOT;

    dim3 blk(256);
    dim3 blk128(128);
    int gS = cdiv_host(NND, 128);                 // 3125 (k_preS2)
    int gB = cdiv_host(NND, 256);                 // 1563 (k_aggE: 256 nodes/block)
    const int GH = 96, GD = 192;

    // ---- bucketed CSR build ----
    hipMemsetAsync(bcnt, 0, (size_t)(2 * NB) * 4, stream);
    k_hist<<<2 * GH, blk, 0, stream>>>(ei_at + NEDGE, ei_ta + NEDGE, bcnt, GH);
    k_scan_nb<<<2, blk, 0, stream>>>(bcnt, bbase, gcur);
    k_dist<<<2 * GD, blk, 0, stream>>>(ei_at, ei_ta, gcur, eb_at, eb_ta, GD);
    k_csrb<<<2 * NB, blk, 0, stream>>>(eb_at, eb_ta, bbase, rp_tx, rp_ad, col_at, col_ta);

    // ---- layer 1 pre-transforms (dual: each x read once) ----
    // SA = x_addr@w1_tx_l (pL-tx)   SB = x_addr@w1_ad_r + b1_ad (pR-ad)
    k_preS2<<<gS, blk128, 0, stream>>>(x_addr, w1_tx_l, SA, w1_ad_r, b1_ad, SB, NADDR);
    // SC = x_tx@w1_ad_l (pL-ad)     SD = x_tx@w1_tx_r + b1_tx (pR-tx)
    k_preS2<<<gS, blk128, 0, stream>>>(x_tx, w1_ad_l, SC, w1_tx_r, b1_tx, SD, NTX);

    // ---- L1 aggs with fused L2 pre-transforms ----
    // TX agg: gather SA over at, self SD. Epilogue: SE = TX@w2_ad_l (P1),
    //         SD = TX@w2_tx_r + b2_tx (P2, in-place on preR).
    k_aggE<0><<<gB, blk, 0, stream>>>(rp_tx, col_at, SA, SD,
                                      w2_ad_l, nullptr, SE,
                                      w2_tx_r, b2_tx, SD, NTX);
    // AD agg: gather SC over ta, self SB. Epilogue: SA = AD@w2_tx_l (P3),
    //         SB = AD@w2_ad_r + b2_ad (P4, in-place on preR).
    k_aggE<0><<<gB, blk, 0, stream>>>(rp_ad, col_ta, SC, SB,
                                      w2_tx_l, nullptr, SA,
                                      w2_ad_r, b2_ad, SB, NADDR);

    // ---- L2 aggs with fused L3 pre-transforms ----
    // TX2 agg: gather SA (P3) over at, self SD (P2). Epilogue: SC = TX2@w3_ad_l (Q1).
    k_aggE<1><<<gB, blk, 0, stream>>>(rp_tx, col_at, SA, SD,
                                      w3_ad_l, nullptr, SC,
                                      nullptr, nullptr, nullptr, NTX);
    // AD2 agg: gather SE (P1) over ta, self SB (P4). Epilogue: SB = AD2@w3_ad_r + b3_ad (Q2).
    k_aggE<1><<<gB, blk, 0, stream>>>(rp_ad, col_ta, SE, SB,
                                      w3_ad_r, b3_ad, SB,
                                      nullptr, nullptr, nullptr, NADDR);

    // ---- L3 agg + classifier ----
    k_aggE<2><<<gB, blk, 0, stream>>>(rp_ad, col_ta, SC, SB,
                                      w_out, b_out, out,
                                      nullptr, nullptr, nullptr, NADDR);
}